// Round 7
// baseline (142.659 us; speedup 1.0000x reference)
//
#include <hip/hip_runtime.h>
#include <hip/hip_bf16.h>

// GRU-D cell: B=16384, I=128, D=16.
// K=2 batch rows per thread; U/W/V/b staged in LDS, read as same-address
// float4 broadcasts. R6 post-mortem: ~5x latency stall factor (each 16-step
// matvec serially pays ~120cy ds_read latency per step). R7: explicit depth-1
// software pipeline -- double-buffered named float4 U registers (ua*/ub*), so
// step d+1's ds_reads issue before step d's FMAs; plus cross-phase prefetch
// of the next matvec's d=0 group under the sigmoid/tanh transcendental block.

constexpr int I_TOT = 128;
constexpr int D_DIM = 16;

__device__ __forceinline__ float4 f4fma(float s, float4 u, float4 a) {
    return make_float4(fmaf(s, u.x, a.x), fmaf(s, u.y, a.y),
                       fmaf(s, u.z, a.z), fmaf(s, u.w, a.w));
}

__device__ __forceinline__ float fast_sigmoid(float x) {
    float e = __expf(-x);
    return __builtin_amdgcn_rcpf(1.0f + e);
}

__device__ __forceinline__ float fast_tanh(float x) {
    x = fminf(fmaxf(x, -10.0f), 10.0f);
    float e = __expf(-2.0f * x);
    return (1.0f - e) * __builtin_amdgcn_rcpf(1.0f + e);
}

__device__ __forceinline__ float4 sig4(float4 x) {
    return make_float4(fast_sigmoid(x.x), fast_sigmoid(x.y),
                       fast_sigmoid(x.z), fast_sigmoid(x.w));
}

__device__ __forceinline__ float4 tanh4(float4 x) {
    return make_float4(fast_tanh(x.x), fast_tanh(x.y),
                       fast_tanh(x.z), fast_tanh(x.w));
}

__device__ __forceinline__ float4 mul4(float4 a, float4 b) {
    return make_float4(a.x * b.x, a.y * b.y, a.z * b.z, a.w * b.w);
}

// o = ht + z*(hh - ht)
__device__ __forceinline__ float4 blend4(float4 z, float4 hh, float4 ht) {
    return make_float4(fmaf(z.x, hh.x - ht.x, ht.x),
                       fmaf(z.y, hh.y - ht.y, ht.y),
                       fmaf(z.z, hh.z - ht.z, ht.z),
                       fmaf(z.w, hh.w - ht.w, ht.w));
}

#define LD4(arr, q) (*reinterpret_cast<const float4*>(&(arr)[4 * (q)]))

__global__ __launch_bounds__(256)
__attribute__((amdgpu_waves_per_eu(2, 8)))
void gru_d_cell(
    const float* __restrict__ h,
    const float* __restrict__ X,
    const float* __restrict__ M,
    const float* __restrict__ gamma_h,
    const float* __restrict__ W_r,
    const float* __restrict__ W_z,
    const float* __restrict__ W_h,
    const float* __restrict__ U_r,
    const float* __restrict__ U_z,
    const float* __restrict__ U_h,
    const float* __restrict__ V_r,
    const float* __restrict__ V_z,
    const float* __restrict__ V_h,
    const float* __restrict__ b_r,
    const float* __restrict__ b_z,
    const float* __restrict__ b_h,
    float* __restrict__ out)
{
    __shared__ float sUr[256];
    __shared__ float sUz[256];
    __shared__ float sUh[256];
    __shared__ float sWr[16], sWz[16], sWh[16];
    __shared__ float sVr[16], sVz[16], sVh[16];
    __shared__ float sbr[16], sbz[16], sbh[16];

    const int i = blockIdx.y;        // block-uniform feature index
    const int t = threadIdx.x;

    sUr[t] = U_r[i * 256 + t];
    sUz[t] = U_z[i * 256 + t];
    sUh[t] = U_h[i * 256 + t];
    if (t < 16) {
        sWr[t] = W_r[i * 16 + t];
        sWz[t] = W_z[i * 16 + t];
        sWh[t] = W_h[i * 16 + t];
        sVr[t] = V_r[i * 16 + t];
        sVz[t] = V_z[i * 16 + t];
        sVh[t] = V_h[i * 16 + t];
        sbr[t] = b_r[i * 16 + t];
        sbz[t] = b_z[i * 16 + t];
        sbh[t] = b_h[i * 16 + t];
    }
    __syncthreads();

    const int b0 = blockIdx.x * 512 + t;
    const int b1 = b0 + 256;
    const size_t base0 = ((size_t)b0 * I_TOT + i) * D_DIM;
    const size_t base1 = ((size_t)b1 * I_TOT + i) * D_DIM;

    // Scattered scalar loads issued first so their latency overlaps hh loads.
    const float xb0 = X[(size_t)b0 * I_TOT + i];
    const float mb0 = M[(size_t)b0 * I_TOT + i];
    const float xb1 = X[(size_t)b1 * I_TOT + i];
    const float mb1 = M[(size_t)b1 * I_TOT + i];

    // hh = h * gamma_h (both rows), named float4s only
    float4 hh0a = mul4(*reinterpret_cast<const float4*>(h + base0 + 0),
                       *reinterpret_cast<const float4*>(gamma_h + base0 + 0));
    float4 hh0b = mul4(*reinterpret_cast<const float4*>(h + base0 + 4),
                       *reinterpret_cast<const float4*>(gamma_h + base0 + 4));
    float4 hh0c = mul4(*reinterpret_cast<const float4*>(h + base0 + 8),
                       *reinterpret_cast<const float4*>(gamma_h + base0 + 8));
    float4 hh0d = mul4(*reinterpret_cast<const float4*>(h + base0 + 12),
                       *reinterpret_cast<const float4*>(gamma_h + base0 + 12));
    float4 hh1a = mul4(*reinterpret_cast<const float4*>(h + base1 + 0),
                       *reinterpret_cast<const float4*>(gamma_h + base1 + 0));
    float4 hh1b = mul4(*reinterpret_cast<const float4*>(h + base1 + 4),
                       *reinterpret_cast<const float4*>(gamma_h + base1 + 4));
    float4 hh1c = mul4(*reinterpret_cast<const float4*>(h + base1 + 8),
                       *reinterpret_cast<const float4*>(gamma_h + base1 + 8));
    float4 hh1d = mul4(*reinterpret_cast<const float4*>(h + base1 + 12),
                       *reinterpret_cast<const float4*>(gamma_h + base1 + 12));

    float4 acc0a, acc0b, acc0c, acc0d, acc1a, acc1b, acc1c, acc1d;
    float4 tmp0a, tmp0b, tmp0c, tmp0d, tmp1a, tmp1b, tmp1c, tmp1d;
    float4 ua0, ua1, ua2, ua3, ub0, ub1, ub2, ub3;   // U double-buffer

#define ACC_INIT(sW, sV, sB)                                                  \
    {                                                                         \
        float4 w = LD4(sW, 0), v = LD4(sV, 0), bb = LD4(sB, 0);               \
        acc0a = f4fma(xb0, w, f4fma(mb0, v, bb));                             \
        acc1a = f4fma(xb1, w, f4fma(mb1, v, bb));                             \
        w = LD4(sW, 1); v = LD4(sV, 1); bb = LD4(sB, 1);                      \
        acc0b = f4fma(xb0, w, f4fma(mb0, v, bb));                             \
        acc1b = f4fma(xb1, w, f4fma(mb1, v, bb));                             \
        w = LD4(sW, 2); v = LD4(sV, 2); bb = LD4(sB, 2);                      \
        acc0c = f4fma(xb0, w, f4fma(mb0, v, bb));                             \
        acc1c = f4fma(xb1, w, f4fma(mb1, v, bb));                             \
        w = LD4(sW, 3); v = LD4(sV, 3); bb = LD4(sB, 3);                      \
        acc0d = f4fma(xb0, w, f4fma(mb0, v, bb));                             \
        acc1d = f4fma(xb1, w, f4fma(mb1, v, bb));                             \
    }

#define LOADU(sU, d, u0, u1, u2, u3)                                          \
    u0 = LD4(sU, 4 * (d) + 0); u1 = LD4(sU, 4 * (d) + 1);                     \
    u2 = LD4(sU, 4 * (d) + 2); u3 = LD4(sU, 4 * (d) + 3);

#define FMAS(s0, s1, u0, u1, u2, u3)                                          \
    acc0a = f4fma(s0, u0, acc0a); acc1a = f4fma(s1, u0, acc1a);               \
    acc0b = f4fma(s0, u1, acc0b); acc1b = f4fma(s1, u1, acc1b);               \
    acc0c = f4fma(s0, u2, acc0c); acc1c = f4fma(s1, u2, acc1c);               \
    acc0d = f4fma(s0, u3, acc0d); acc1d = f4fma(s1, u3, acc1d);

// Pipelined matvec; assumes d=0's group is ALREADY loaded into ua0..ua3.
// Step d: issue loads for d+1 into the idle buffer, then FMA with current.
#define MATVEC_TAIL(sU, A0, B0, C0, D0, A1, B1, C1, D1)                       \
    LOADU(sU, 1,  ub0, ub1, ub2, ub3)  FMAS(A0.x, A1.x, ua0, ua1, ua2, ua3)  \
    LOADU(sU, 2,  ua0, ua1, ua2, ua3)  FMAS(A0.y, A1.y, ub0, ub1, ub2, ub3)  \
    LOADU(sU, 3,  ub0, ub1, ub2, ub3)  FMAS(A0.z, A1.z, ua0, ua1, ua2, ua3)  \
    LOADU(sU, 4,  ua0, ua1, ua2, ua3)  FMAS(A0.w, A1.w, ub0, ub1, ub2, ub3)  \
    LOADU(sU, 5,  ub0, ub1, ub2, ub3)  FMAS(B0.x, B1.x, ua0, ua1, ua2, ua3)  \
    LOADU(sU, 6,  ua0, ua1, ua2, ua3)  FMAS(B0.y, B1.y, ub0, ub1, ub2, ub3)  \
    LOADU(sU, 7,  ub0, ub1, ub2, ub3)  FMAS(B0.z, B1.z, ua0, ua1, ua2, ua3)  \
    LOADU(sU, 8,  ua0, ua1, ua2, ua3)  FMAS(B0.w, B1.w, ub0, ub1, ub2, ub3)  \
    LOADU(sU, 9,  ub0, ub1, ub2, ub3)  FMAS(C0.x, C1.x, ua0, ua1, ua2, ua3)  \
    LOADU(sU, 10, ua0, ua1, ua2, ua3)  FMAS(C0.y, C1.y, ub0, ub1, ub2, ub3)  \
    LOADU(sU, 11, ub0, ub1, ub2, ub3)  FMAS(C0.z, C1.z, ua0, ua1, ua2, ua3)  \
    LOADU(sU, 12, ua0, ua1, ua2, ua3)  FMAS(C0.w, C1.w, ub0, ub1, ub2, ub3)  \
    LOADU(sU, 13, ub0, ub1, ub2, ub3)  FMAS(D0.x, D1.x, ua0, ua1, ua2, ua3)  \
    LOADU(sU, 14, ua0, ua1, ua2, ua3)  FMAS(D0.y, D1.y, ub0, ub1, ub2, ub3)  \
    LOADU(sU, 15, ub0, ub1, ub2, ub3)  FMAS(D0.z, D1.z, ua0, ua1, ua2, ua3)  \
    FMAS(D0.w, D1.w, ub0, ub1, ub2, ub3)

    // ---- Phase 1: accr = x*Wr + m*Vr + br + hh @ Ur ----
    LOADU(sUr, 0, ua0, ua1, ua2, ua3)
    ACC_INIT(sWr, sVr, sbr)
    MATVEC_TAIL(sUr, hh0a, hh0b, hh0c, hh0d, hh1a, hh1b, hh1c, hh1d)

    // Prefetch phase-2's d=0 group; its latency hides under 32 sigmoids.
    LOADU(sUh, 0, ua0, ua1, ua2, ua3)
    tmp0a = mul4(sig4(acc0a), hh0a); tmp0b = mul4(sig4(acc0b), hh0b);
    tmp0c = mul4(sig4(acc0c), hh0c); tmp0d = mul4(sig4(acc0d), hh0d);
    tmp1a = mul4(sig4(acc1a), hh1a); tmp1b = mul4(sig4(acc1b), hh1b);
    tmp1c = mul4(sig4(acc1c), hh1c); tmp1d = mul4(sig4(acc1d), hh1d);

    // ---- Phase 2: acch = x*Wh + m*Vh + bh + rhh @ Uh ----
    ACC_INIT(sWh, sVh, sbh)
    MATVEC_TAIL(sUh, tmp0a, tmp0b, tmp0c, tmp0d, tmp1a, tmp1b, tmp1c, tmp1d)

    // Prefetch phase-3's d=0 group; latency hides under 32 tanhs.
    LOADU(sUz, 0, ua0, ua1, ua2, ua3)
    tmp0a = tanh4(acc0a); tmp0b = tanh4(acc0b);
    tmp0c = tanh4(acc0c); tmp0d = tanh4(acc0d);
    tmp1a = tanh4(acc1a); tmp1b = tanh4(acc1b);
    tmp1c = tanh4(acc1c); tmp1d = tanh4(acc1d);

    // ---- Phase 3: accz = x*Wz + m*Vz + bz + hh @ Uz ----
    ACC_INIT(sWz, sVz, sbz)
    MATVEC_TAIL(sUz, hh0a, hh0b, hh0c, hh0d, hh1a, hh1b, hh1c, hh1d)

    // out = ht + sigmoid(accz) * (hh - ht)
    {
        float4 o0 = blend4(sig4(acc0a), hh0a, tmp0a);
        float4 o1 = blend4(sig4(acc0b), hh0b, tmp0b);
        float4 o2 = blend4(sig4(acc0c), hh0c, tmp0c);
        float4 o3 = blend4(sig4(acc0d), hh0d, tmp0d);
        *reinterpret_cast<float4*>(out + base0 + 0)  = o0;
        *reinterpret_cast<float4*>(out + base0 + 4)  = o1;
        *reinterpret_cast<float4*>(out + base0 + 8)  = o2;
        *reinterpret_cast<float4*>(out + base0 + 12) = o3;
    }
    {
        float4 o0 = blend4(sig4(acc1a), hh1a, tmp1a);
        float4 o1 = blend4(sig4(acc1b), hh1b, tmp1b);
        float4 o2 = blend4(sig4(acc1c), hh1c, tmp1c);
        float4 o3 = blend4(sig4(acc1d), hh1d, tmp1d);
        *reinterpret_cast<float4*>(out + base1 + 0)  = o0;
        *reinterpret_cast<float4*>(out + base1 + 4)  = o1;
        *reinterpret_cast<float4*>(out + base1 + 8)  = o2;
        *reinterpret_cast<float4*>(out + base1 + 12) = o3;
    }
}

extern "C" void kernel_launch(void* const* d_in, const int* in_sizes, int n_in,
                              void* d_out, int out_size, void* d_ws, size_t ws_size,
                              hipStream_t stream) {
    const float* h       = (const float*)d_in[0];
    const float* X       = (const float*)d_in[1];
    const float* M       = (const float*)d_in[2];
    const float* gamma_h = (const float*)d_in[3];
    const float* W_r     = (const float*)d_in[4];
    const float* W_z     = (const float*)d_in[5];
    const float* W_h     = (const float*)d_in[6];
    const float* U_r     = (const float*)d_in[7];
    const float* U_z     = (const float*)d_in[8];
    const float* U_h     = (const float*)d_in[9];
    const float* V_r     = (const float*)d_in[10];
    const float* V_z     = (const float*)d_in[11];
    const float* V_h     = (const float*)d_in[12];
    const float* b_r     = (const float*)d_in[13];
    const float* b_z     = (const float*)d_in[14];
    const float* b_h     = (const float*)d_in[15];
    float* out = (float*)d_out;

    const int B = 16384;
    dim3 grid(B / 512, I_TOT);   // (32, 128)
    dim3 block(256);
    gru_d_cell<<<grid, block, 0, stream>>>(h, X, M, gamma_h,
                                           W_r, W_z, W_h,
                                           U_r, U_z, U_h,
                                           V_r, V_z, V_h,
                                           b_r, b_z, b_h,
                                           out);
}